// Round 3
// baseline (611.558 us; speedup 1.0000x reference)
//
#include <hip/hip_runtime.h>
#include <cstddef>

#define N 1024
#define DN 128      // NODE_DIM
#define DE 16       // EDGE_DIM
#define DM 64       // MSG_DIM
#define TSTEPS 3
#define INDIM 272   // 2*DN + DE

// ---------------------------------------------------------------------------
// kInit: P[i,0:64]=hi, P[i,64:128]=hj, P[i,128:512]=gh+b_hh, from H=X.
// One row per block, 512 threads = one output column each.
// ---------------------------------------------------------------------------
__global__ __launch_bounds__(512, 4) void kInit(const float* __restrict__ H,
                                                const float* __restrict__ W1,
                                                const float* __restrict__ W_hh,
                                                const float* __restrict__ b_hh,
                                                float* __restrict__ P) {
  int i = blockIdx.x;
  int t = threadIdx.x;
  __shared__ float h[DN];
  if (t < DN) h[t] = H[(size_t)i * DN + t];
  __syncthreads();

  const float* w;
  float acc;
  if (t < 64)       { w = W1 + (size_t)t * INDIM;              acc = 0.f; }
  else if (t < 128) { w = W1 + (size_t)(t - 64) * INDIM + 128; acc = 0.f; }
  else              { w = W_hh + (size_t)(t - 128) * DN;       acc = b_hh[t - 128]; }
  const float4* w4 = (const float4*)w;
  float a0 = 0.f, a1 = 0.f;
  #pragma unroll
  for (int k4 = 0; k4 < DN / 8; ++k4) {
    float4 wv0 = w4[2 * k4];
    float4 wv1 = w4[2 * k4 + 1];
    a0 = fmaf(h[k4 * 8 + 0], wv0.x, a0);
    a1 = fmaf(h[k4 * 8 + 4], wv1.x, a1);
    a0 = fmaf(h[k4 * 8 + 1], wv0.y, a0);
    a1 = fmaf(h[k4 * 8 + 5], wv1.y, a1);
    a0 = fmaf(h[k4 * 8 + 2], wv0.z, a0);
    a1 = fmaf(h[k4 * 8 + 6], wv1.z, a1);
    a0 = fmaf(h[k4 * 8 + 3], wv0.w, a0);
    a1 = fmaf(h[k4 * 8 + 7], wv1.w, a1);
  }
  P[(size_t)i * 512 + t] = acc + a0 + a1;
}

// ---------------------------------------------------------------------------
// kStep: fused per-row step. Block = row i, 512 threads (8 waves).
//  Phase B: S[i,m] = sum_j A[i,j]*relu(hi[i,m]+hj[j,m]+E[i,j,:]@We[m,:]+b1[m])
//           thread: m = t&63 (one m), jg = t>>6 (8 j-lanes), 128 j's each.
//  Phase C: M = S@W2.T + deg*b2 ; gi = M@W_ih.T + b_ih ; GRU -> Hout[i].
//  Phase A: Pnext[i] from new H row (skipped on last step via doPA).
// ---------------------------------------------------------------------------
__global__ __launch_bounds__(512, 4) void kStep(const float* __restrict__ Pcur,
                                                const float* __restrict__ E,
                                                const float* __restrict__ W1,
                                                const float* __restrict__ b1,
                                                const int* __restrict__ A,
                                                const float* __restrict__ W2,
                                                const float* __restrict__ b2,
                                                const float* __restrict__ W_ih,
                                                const float* __restrict__ b_ih,
                                                const float* __restrict__ W_hh,
                                                const float* __restrict__ b_hh,
                                                const float* __restrict__ Hin,
                                                float* __restrict__ Hout,
                                                float* __restrict__ Pnext,
                                                int doPA) {
  int i  = blockIdx.x;
  int t  = threadIdx.x;
  int m  = t & 63;   // message dim
  int jg = t >> 6;   // 0..7

  __shared__ int   sA[N];
  __shared__ float red[8][DM];
  __shared__ float dred[8];
  __shared__ float sS[DM];
  __shared__ float sM[DM];
  __shared__ float sGi[384];
  __shared__ float sH[DN];
  __shared__ float sdeg;

  // stage A row
  const int* Arow = A + (size_t)i * N;
  sA[t]       = Arow[t];
  sA[t + 512] = Arow[t + 512];

  // We row for this thread's m (16 VGPRs)
  float we[16];
  {
    const float4* wr4 = (const float4*)(W1 + (size_t)m * INDIM + 256);
    #pragma unroll
    for (int q = 0; q < 4; ++q) {
      float4 v = wr4[q];
      we[q * 4 + 0] = v.x;
      we[q * 4 + 1] = v.y;
      we[q * 4 + 2] = v.z;
      we[q * 4 + 3] = v.w;
    }
  }
  float hib = Pcur[(size_t)i * 512 + m] + b1[m];

  __syncthreads();

  float s = 0.f;
  int   dg = 0;

  const float4* e4  = (const float4*)(E + ((size_t)i * N + jg) * DE);
  const float*  hjp = Pcur + (size_t)jg * 512 + 64 + m;

  #pragma unroll 2
  for (int jt = 0; jt < N / 8; ++jt) {
    float4 q0 = e4[0], q1 = e4[1], q2 = e4[2], q3 = e4[3];
    float  hj = *hjp;
    int    a  = sA[jt * 8 + jg];
    if (m == 0) dg += a;

    float acc = hib + hj;
    acc = fmaf(q0.x, we[0],  acc);
    acc = fmaf(q0.y, we[1],  acc);
    acc = fmaf(q0.z, we[2],  acc);
    acc = fmaf(q0.w, we[3],  acc);
    acc = fmaf(q1.x, we[4],  acc);
    acc = fmaf(q1.y, we[5],  acc);
    acc = fmaf(q1.z, we[6],  acc);
    acc = fmaf(q1.w, we[7],  acc);
    acc = fmaf(q2.x, we[8],  acc);
    acc = fmaf(q2.y, we[9],  acc);
    acc = fmaf(q2.z, we[10], acc);
    acc = fmaf(q2.w, we[11], acc);
    acc = fmaf(q3.x, we[12], acc);
    acc = fmaf(q3.y, we[13], acc);
    acc = fmaf(q3.z, we[14], acc);
    acc = fmaf(q3.w, we[15], acc);

    s = fmaf((float)a, fmaxf(acc, 0.f), s);

    e4  += 8 * DE / 4;   // advance 8 E-rows
    hjp += 8 * 512;      // advance 8 P-rows
  }

  red[jg][m] = s;
  if (m == 0) dred[jg] = (float)dg;
  __syncthreads();

  // S reduce
  if (t < DM) {
    float acc = 0.f;
    #pragma unroll
    for (int r = 0; r < 8; ++r) acc += red[r][t];
    sS[t] = acc;
  }
  if (t == DM) {
    float d = 0.f;
    #pragma unroll
    for (int r = 0; r < 8; ++r) d += dred[r];
    sdeg = d;
  }
  __syncthreads();

  // M = S @ W2.T + deg*b2
  if (t < DM) {
    float acc = sdeg * b2[t];
    const float4* w4 = (const float4*)(W2 + (size_t)t * DM);
    #pragma unroll
    for (int k4 = 0; k4 < DM / 4; ++k4) {
      float4 wv = w4[k4];
      acc = fmaf(sS[k4 * 4 + 0], wv.x, acc);
      acc = fmaf(sS[k4 * 4 + 1], wv.y, acc);
      acc = fmaf(sS[k4 * 4 + 2], wv.z, acc);
      acc = fmaf(sS[k4 * 4 + 3], wv.w, acc);
    }
    sM[t] = acc;
  }
  __syncthreads();

  // gi = M @ W_ih.T + b_ih
  if (t < 384) {
    float acc = b_ih[t];
    const float4* w4 = (const float4*)(W_ih + (size_t)t * DM);
    #pragma unroll
    for (int k4 = 0; k4 < DM / 4; ++k4) {
      float4 wv = w4[k4];
      acc = fmaf(sM[k4 * 4 + 0], wv.x, acc);
      acc = fmaf(sM[k4 * 4 + 1], wv.y, acc);
      acc = fmaf(sM[k4 * 4 + 2], wv.z, acc);
      acc = fmaf(sM[k4 * 4 + 3], wv.w, acc);
    }
    sGi[t] = acc;
  }
  __syncthreads();

  // GRU gates
  if (t < DN) {
    float ghr = Pcur[(size_t)i * 512 + 128 + t];
    float ghz = Pcur[(size_t)i * 512 + 256 + t];
    float ghn = Pcur[(size_t)i * 512 + 384 + t];
    float gir = sGi[t], giz = sGi[128 + t], gin = sGi[256 + t];
    float r = 1.f / (1.f + expf(-(gir + ghr)));
    float z = 1.f / (1.f + expf(-(giz + ghz)));
    float n = tanhf(gin + r * ghn);
    float h = Hin[(size_t)i * DN + t];
    float hn = (1.f - z) * n + z * h;
    sH[t] = hn;
    Hout[(size_t)i * DN + t] = hn;
  }
  __syncthreads();

  // Phase A for next step: Pnext[i, t]
  if (doPA) {
    const float* w;
    float acc;
    if (t < 64)       { w = W1 + (size_t)t * INDIM;              acc = 0.f; }
    else if (t < 128) { w = W1 + (size_t)(t - 64) * INDIM + 128; acc = 0.f; }
    else              { w = W_hh + (size_t)(t - 128) * DN;       acc = b_hh[t - 128]; }
    const float4* w4 = (const float4*)w;
    float a0 = 0.f, a1 = 0.f;
    #pragma unroll
    for (int k4 = 0; k4 < DN / 8; ++k4) {
      float4 wv0 = w4[2 * k4];
      float4 wv1 = w4[2 * k4 + 1];
      a0 = fmaf(sH[k4 * 8 + 0], wv0.x, a0);
      a1 = fmaf(sH[k4 * 8 + 4], wv1.x, a1);
      a0 = fmaf(sH[k4 * 8 + 1], wv0.y, a0);
      a1 = fmaf(sH[k4 * 8 + 5], wv1.y, a1);
      a0 = fmaf(sH[k4 * 8 + 2], wv0.z, a0);
      a1 = fmaf(sH[k4 * 8 + 6], wv1.z, a1);
      a0 = fmaf(sH[k4 * 8 + 3], wv0.w, a0);
      a1 = fmaf(sH[k4 * 8 + 7], wv1.w, a1);
    }
    Pnext[(size_t)i * 512 + t] = acc + a0 + a1;
  }
}

// ---------------------------------------------------------------------------
extern "C" void kernel_launch(void* const* d_in, const int* in_sizes, int n_in,
                              void* d_out, int out_size, void* d_ws, size_t ws_size,
                              hipStream_t stream) {
  const float* X    = (const float*)d_in[0];
  const int*   A    = (const int*)  d_in[1];
  const float* E    = (const float*)d_in[2];
  const float* W1   = (const float*)d_in[3];
  const float* b1   = (const float*)d_in[4];
  const float* W2   = (const float*)d_in[5];
  const float* b2   = (const float*)d_in[6];
  const float* W_ih = (const float*)d_in[7];
  const float* b_ih = (const float*)d_in[8];
  const float* W_hh = (const float*)d_in[9];
  const float* b_hh = (const float*)d_in[10];
  float* out = (float*)d_out;

  float* ws   = (float*)d_ws;
  float* Hbuf = ws;                 // N*DN   = 131072 floats
  float* P0   = Hbuf + N * DN;      // N*512  = 524288 floats
  float* P1   = P0 + N * 512;       // N*512  = 524288 floats

  kInit<<<N, 512, 0, stream>>>(X, W1, W_hh, b_hh, P0);

  const float* Hin = X;
  float* Pc = P0;
  float* Pn = P1;
  for (int step = 0; step < TSTEPS; ++step) {
    int last = (step == TSTEPS - 1);
    float* Hout = last ? out : Hbuf;
    kStep<<<N, 512, 0, stream>>>(Pc, E, W1, b1, A, W2, b2, W_ih, b_ih,
                                 W_hh, b_hh, Hin, Hout, Pn, last ? 0 : 1);
    Hin = Hbuf;
    float* tmp = Pc; Pc = Pn; Pn = tmp;
  }
}